// Round 1
// baseline (1350.557 us; speedup 1.0000x reference)
//
#include <hip/hip_runtime.h>
#include <hip/hip_bf16.h>
#include <cstdint>

typedef __hip_bfloat16 bf16;

__device__ __forceinline__ float bf2f(bf16 v) { return __bfloat162float(v); }
__device__ __forceinline__ bf16  f2bf(float v) { return __float2bfloat16(v); }

// window-order row m -> token index (t*4096 + p)
__device__ __forceinline__ int win_to_token(int m) {
  int n = m >> 8, l = m & 255;
  int t = n >> 4, win = n & 15;
  int wi = win >> 2, wj = win & 3;
  int u = l >> 4, v = l & 15;
  return (t << 12) | ((wi * 16 + u) << 6) | (wj * 16 + v);
}

// ---------------- kernel 1: pool + selector MLP + gumbel mask ----------------
__global__ __launch_bounds__(64) void k_selector(
    const float* __restrict__ x, const float* __restrict__ gu,
    const float* __restrict__ s1w, const float* __restrict__ s1b,
    const float* __restrict__ s2w, const float* __restrict__ s2b,
    const float* __restrict__ s3w, const float* __restrict__ s3b,
    float* __restrict__ f1o, float* __restrict__ f2o, float* __restrict__ f3o,
    float* __restrict__ maskp) {
  int t = blockIdx.x, lane = threadIdx.x;
  int th = t >> 2, tw = t & 3;
  __shared__ float pooled[192];
  __shared__ float f1s[64], f2s[32], f3s[2];
  for (int o = lane; o < 192; o += 64) {
    int ch = o % 3, j = (o / 3) & 7, i = o / 24;
    const float* xp = x + ch * 65536 + (th * 64 + i * 8) * 256 + (tw * 64 + j * 8);
    float s = 0.f;
    for (int a = 0; a < 8; ++a)
      for (int b = 0; b < 8; ++b) s += xp[a * 256 + b];
    pooled[o] = s * (1.0f / 64.0f);
  }
  __syncthreads();
  {
    float s = s1b[lane];
    for (int k = 0; k < 192; ++k) s = fmaf(pooled[k], s1w[k * 64 + lane], s);
    f1o[t * 64 + lane] = s;
    f1s[lane] = fmaxf(s, 0.f);
  }
  __syncthreads();
  if (lane < 32) {
    float s = s2b[lane];
    for (int k = 0; k < 64; ++k) s = fmaf(f1s[k], s2w[k * 32 + lane], s);
    f2o[t * 32 + lane] = s;
    f2s[lane] = fmaxf(s, 0.f);
  }
  __syncthreads();
  if (lane < 2) {
    float s = s3b[lane];
    for (int k = 0; k < 32; ++k) s = fmaf(f2s[k], s3w[k * 2 + lane], s);
    f3o[t * 2 + lane] = s;
    f3s[lane] = s;
  }
  __syncthreads();
  if (lane == 0) {
    float g0 = -logf(-logf(gu[t * 2 + 0] + 1e-10f) + 1e-10f);
    float g1 = -logf(-logf(gu[t * 2 + 1] + 1e-10f) + 1e-10f);
    maskp[t] = (f3s[1] + g1 > f3s[0] + g0) ? 1.0f : 0.0f;
  }
}

// ---------------- kernel 2: embed (3->180) + LN1 stats ----------------
__global__ __launch_bounds__(256) void k_embed(
    const float* __restrict__ x, const float* __restrict__ ew,
    const float* __restrict__ eb, float* __restrict__ tok,
    float* __restrict__ stats) {
  int token = blockIdx.x * 4 + (threadIdx.x >> 6);
  int lane = threadIdx.x & 63;
  int t = token >> 12, p = token & 4095;
  int r = p >> 6, c = p & 63;
  int gh = (t >> 2) * 64 + r, gw = (t & 3) * 64 + c;
  float x0 = x[gh * 256 + gw];
  float x1 = x[65536 + gh * 256 + gw];
  float x2 = x[131072 + gh * 256 + gw];
  float s = 0.f, s2 = 0.f;
#pragma unroll
  for (int i = 0; i < 3; ++i) {
    int e = lane + i * 64;
    if (e < 180) {
      float v = eb[e];
      v = fmaf(x0, ew[e], v);
      v = fmaf(x1, ew[180 + e], v);
      v = fmaf(x2, ew[360 + e], v);
      tok[(size_t)token * 180 + e] = v;
      s += v; s2 = fmaf(v, v, s2);
    }
  }
#pragma unroll
  for (int off = 32; off; off >>= 1) { s += __shfl_xor(s, off); s2 += __shfl_xor(s2, off); }
  if (lane == 0) {
    float mu = s * (1.f / 180.f);
    float var = s2 * (1.f / 180.f) - mu * mu;
    stats[token * 2] = mu;
    stats[token * 2 + 1] = rsqrtf(var + 1e-5f);
  }
}

// ---------------- LN2 stats (over current tok) ----------------
__global__ __launch_bounds__(256) void k_ln_stats(
    const float* __restrict__ tok, float* __restrict__ stats) {
  int token = blockIdx.x * 4 + (threadIdx.x >> 6);
  int lane = threadIdx.x & 63;
  float s = 0.f, s2 = 0.f;
#pragma unroll
  for (int i = 0; i < 3; ++i) {
    int e = lane + i * 64;
    if (e < 180) {
      float v = tok[(size_t)token * 180 + e];
      s += v; s2 = fmaf(v, v, s2);
    }
  }
#pragma unroll
  for (int off = 32; off; off >>= 1) { s += __shfl_xor(s, off); s2 += __shfl_xor(s2, off); }
  if (lane == 0) {
    float mu = s * (1.f / 180.f);
    float var = s2 * (1.f / 180.f) - mu * mu;
    stats[token * 2] = mu;
    stats[token * 2 + 1] = rsqrtf(var + 1e-5f);
  }
}

// ---------------- generic tiled GEMM: C[M=65536 x N] = op(A)[.,K] * B[K,N] ----------------
template <bool A_BF16, bool LN, bool MAP_A, bool MAP_C, bool GELU_E, bool ACCUM, bool OUT_BF16>
__global__ __launch_bounds__(256) void k_gemm(
    const void* __restrict__ Ap, const float* __restrict__ Bw,
    const float* __restrict__ bias, const float* __restrict__ stats,
    const float* __restrict__ lng, const float* __restrict__ lnb,
    void* __restrict__ Cp, int N, int K) {
  __shared__ float As[64 * 17];
  __shared__ float Bs[16 * 64];
  const int tid = threadIdx.x;
  const int tx = tid & 15, ty = tid >> 4;
  const int m0 = blockIdx.x * 64, n0 = blockIdx.y * 64;
  float acc[4][4] = {};
  for (int k0 = 0; k0 < K; k0 += 16) {
#pragma unroll
    for (int i = 0; i < 4; ++i) {
      int flat = tid + i * 256;
      int row = flat >> 4, kk = flat & 15;
      int k = k0 + kk;
      float a = 0.f;
      if (k < K) {
        int arow = MAP_A ? win_to_token(m0 + row) : (m0 + row);
        if (A_BF16) a = bf2f(((const bf16*)Ap)[(size_t)arow * K + k]);
        else        a = ((const float*)Ap)[(size_t)arow * K + k];
        if (LN) {
          float mu = stats[arow * 2], rs = stats[arow * 2 + 1];
          a = (a - mu) * rs * lng[k] + lnb[k];
        }
      }
      As[row * 17 + kk] = a;
    }
#pragma unroll
    for (int i = 0; i < 4; ++i) {
      int flat = tid + i * 256;
      int kk = flat >> 6, col = flat & 63;
      int k = k0 + kk, n = n0 + col;
      Bs[kk * 64 + col] = (k < K && n < N) ? Bw[(size_t)k * N + n] : 0.f;
    }
    __syncthreads();
#pragma unroll
    for (int kk = 0; kk < 16; ++kk) {
      float av_[4], bv[4];
#pragma unroll
      for (int i = 0; i < 4; ++i) av_[i] = As[(ty * 4 + i) * 17 + kk];
#pragma unroll
      for (int j = 0; j < 4; ++j) bv[j] = Bs[kk * 64 + tx * 4 + j];
#pragma unroll
      for (int i = 0; i < 4; ++i)
#pragma unroll
        for (int j = 0; j < 4; ++j) acc[i][j] = fmaf(av_[i], bv[j], acc[i][j]);
    }
    __syncthreads();
  }
#pragma unroll
  for (int i = 0; i < 4; ++i) {
    int m = m0 + ty * 4 + i;
    int crow = MAP_C ? win_to_token(m) : m;
#pragma unroll
    for (int j = 0; j < 4; ++j) {
      int n = n0 + tx * 4 + j;
      if (n >= N) continue;
      float v = acc[i][j] + bias[n];
      if (GELU_E) {
        float u = 0.7978845608028654f * (v + 0.044715f * v * v * v);
        v = 0.5f * v * (1.f + tanhf(u));
      }
      if (ACCUM)         ((float*)Cp)[(size_t)crow * N + n] += v;
      else if (OUT_BF16) ((bf16*)Cp)[(size_t)crow * N + n] = f2bf(v);
      else               ((float*)Cp)[(size_t)crow * N + n] = v;
    }
  }
}

// ---------------- attention: one block per (window, head), thread = query row ----------------
__global__ __launch_bounds__(256) void k_attn(const bf16* __restrict__ qkv,
                                              bf16* __restrict__ av) {
  int blk = blockIdx.x;
  int n = blk / 6, hd = blk % 6;
  int l = threadIdx.x;
  const float scale = 0.18257418583505536f;  // 1/sqrt(30)
  float q[30];
  const bf16* qrow = qkv + ((size_t)n * 256 + l) * 540 + hd * 30;
#pragma unroll
  for (int d = 0; d < 30; ++d) q[d] = bf2f(qrow[d]) * scale;
  __shared__ float ks[64][32];
  __shared__ float vs[64][32];
  float m_run = -1e30f, l_run = 0.f;
  float acc[30];
#pragma unroll
  for (int d = 0; d < 30; ++d) acc[d] = 0.f;
  for (int mt = 0; mt < 256; mt += 64) {
    __syncthreads();
    for (int idx = threadIdx.x; idx < 64 * 30; idx += 256) {
      int row = idx / 30, d = idx % 30;
      const bf16* base = qkv + ((size_t)n * 256 + mt + row) * 540 + hd * 30;
      ks[row][d] = bf2f(base[180 + d]);
      vs[row][d] = bf2f(base[360 + d]);
    }
    __syncthreads();
    for (int mm = 0; mm < 64; ++mm) {
      float s = 0.f;
#pragma unroll
      for (int d = 0; d < 30; ++d) s = fmaf(q[d], ks[mm][d], s);
      float mnew = fmaxf(m_run, s);
      float corr = __expf(m_run - mnew);
      float p = __expf(s - mnew);
      l_run = fmaf(l_run, corr, p);
#pragma unroll
      for (int d = 0; d < 30; ++d) acc[d] = fmaf(acc[d], corr, p * vs[mm][d]);
      m_run = mnew;
    }
  }
  float inv = 1.f / l_run;
  bf16* out = av + ((size_t)n * 256 + l) * 180 + hd * 30;
#pragma unroll
  for (int d = 0; d < 30; ++d) out[d] = f2bf(acc[d] * inv);
}

// ---------------- bicubic weights (jax Keys a=-0.5, half-pixel, edge renorm) ----------------
__device__ const float c_cubw[4][4] = {
    {-0.0439453125f, 0.3896484375f, 0.7275390625f, -0.0732421875f},  // phase 0: taps r-2..r+1
    {-0.0068359375f, 0.0908203125f, 0.9638671875f, -0.0478515625f},  // phase 1: taps r-2..r+1
    {-0.0478515625f, 0.9638671875f, 0.0908203125f, -0.0068359375f},  // phase 2: taps r-1..r+2
    {-0.0732421875f, 0.7275390625f, 0.3896484375f, -0.0439453125f},  // phase 3: taps r-1..r+2
};

__device__ __forceinline__ void cubw(int r, int ph, float* w, int& base) {
  base = r + ((ph < 2) ? -2 : -1);
  float sum = 0.f;
#pragma unroll
  for (int i = 0; i < 4; ++i) {
    int idx = base + i;
    float wi = (idx >= 0 && idx < 64) ? c_cubw[ph][i] : 0.f;
    w[i] = wi; sum += wi;
  }
  float inv = 1.f / sum;
#pragma unroll
  for (int i = 0; i < 4; ++i) w[i] *= inv;
}

// ---------------- final: up-proj + pixel shuffle + bicubic + blend ----------------
__global__ __launch_bounds__(64) void k_final(
    const float* __restrict__ tok, const float* __restrict__ x,
    const float* __restrict__ upw, const float* __restrict__ upb,
    const float* __restrict__ maskp, float* __restrict__ sr) {
  int token = blockIdx.x;
  int lane = threadIdx.x;
  int t = token >> 12, p = token & 4095;
  int r = p >> 6, c = p & 63;
  int th = t >> 2, tw = t & 3;
  __shared__ float trow[180];
  for (int e = lane; e < 180; e += 64) trow[e] = tok[(size_t)token * 180 + e];
  __syncthreads();
  if (lane >= 48) return;
  int e = lane;
  float s = upb[e];
  for (int k = 0; k < 180; ++k) s = fmaf(trow[k], upw[k * 48 + e], s);
  int ch = e % 3, b = (e / 3) & 3, a = e / 12;
  float wy[4], wx[4];
  int yb, xb;
  cubw(r, a, wy, yb);
  cubw(c, b, wx, xb);
  const float* xc = x + ch * 65536;
  float neg = 0.f;
#pragma unroll
  for (int i = 0; i < 4; ++i) {
    int yi = yb + i;
    if (yi < 0 || yi > 63) continue;
    float rowsum = 0.f;
#pragma unroll
    for (int j = 0; j < 4; ++j) {
      int xj = xb + j;
      if (xj < 0 || xj > 63) continue;
      rowsum = fmaf(wx[j], xc[(th * 64 + yi) * 256 + tw * 64 + xj], rowsum);
    }
    neg = fmaf(wy[i], rowsum, neg);
  }
  float m = maskp[t];
  float outv = m * s + (1.f - m) * neg;
  int R = r * 4 + a, C = c * 4 + b;
  sr[(size_t)ch * 1048576 + (size_t)(th * 256 + R) * 1024 + (tw * 256 + C)] = outv;
}

// ---------------- launcher ----------------
extern "C" void kernel_launch(void* const* d_in, const int* in_sizes, int n_in,
                              void* d_out, int out_size, void* d_ws, size_t ws_size,
                              hipStream_t stream) {
  const float* x     = (const float*)d_in[0];
  const float* gu    = (const float*)d_in[1];
  const float* s1w   = (const float*)d_in[2];
  const float* s1b   = (const float*)d_in[3];
  const float* s2w   = (const float*)d_in[4];
  const float* s2b   = (const float*)d_in[5];
  const float* s3w   = (const float*)d_in[6];
  const float* s3b   = (const float*)d_in[7];
  const float* ew    = (const float*)d_in[8];
  const float* ebias = (const float*)d_in[9];
  const float* ln1g  = (const float*)d_in[10];
  const float* ln1b  = (const float*)d_in[11];
  const float* qkvw  = (const float*)d_in[12];
  const float* qkvb  = (const float*)d_in[13];
  const float* projw = (const float*)d_in[14];
  const float* projb = (const float*)d_in[15];
  const float* ln2g  = (const float*)d_in[16];
  const float* ln2b  = (const float*)d_in[17];
  const float* mlp1w = (const float*)d_in[18];
  const float* mlp1b = (const float*)d_in[19];
  const float* mlp2w = (const float*)d_in[20];
  const float* mlp2b = (const float*)d_in[21];
  const float* upw   = (const float*)d_in[22];
  const float* upb   = (const float*)d_in[23];

  float* out = (float*)d_out;
  float* sr  = out;                 // 3*1024*1024
  float* f3o = out + 3145728;       // 16*2
  float* f2o = f3o + 32;            // 16*32
  float* f1o = f2o + 512;           // 16*64

  char* ws = (char*)d_ws;
  float* tok   = (float*)(ws);                  // 65536*180 fp32  = 47185920 B
  float* stats = (float*)(ws + 47185920);       // 65536*2  fp32  = 524288 B
  bf16*  qkv   = (bf16*)(ws + 47710208);        // 65536*540 bf16 = 70778880 B
  bf16*  mid   = qkv;                           // reused: 65536*360 bf16 = 47185920 B
  bf16*  avb   = (bf16*)(ws + 118489088);       // 65536*180 bf16 = 23592960 B
  float* maskp = (float*)(ws + 142082048);      // 16 fp32

  k_selector<<<16, 64, 0, stream>>>(x, gu, s1w, s1b, s2w, s2b, s3w, s3b, f1o, f2o, f3o, maskp);
  k_embed<<<16384, 256, 0, stream>>>(x, ew, ebias, tok, stats);
  // qkv = LN1(tok)[window order] @ qkv_w + qkv_b   (A fp32+LN+mapA, out bf16)
  k_gemm<false, true, true, false, false, false, true><<<dim3(1024, 9), 256, 0, stream>>>(
      tok, qkvw, qkvb, stats, ln1g, ln1b, qkv, 540, 180);
  k_attn<<<1536, 256, 0, stream>>>(qkv, avb);
  // tok += av @ proj_w + proj_b   (A bf16, mapC, accumulate fp32)
  k_gemm<true, false, false, true, false, true, false><<<dim3(1024, 3), 256, 0, stream>>>(
      avb, projw, projb, nullptr, nullptr, nullptr, tok, 180, 180);
  k_ln_stats<<<16384, 256, 0, stream>>>(tok, stats);
  // mid = gelu(LN2(tok) @ mlp1_w + mlp1_b)   (A fp32+LN, gelu, out bf16)
  k_gemm<false, true, false, false, true, false, true><<<dim3(1024, 6), 256, 0, stream>>>(
      tok, mlp1w, mlp1b, stats, ln2g, ln2b, mid, 360, 180);
  // tok += mid @ mlp2_w + mlp2_b   (A bf16, accumulate fp32)
  k_gemm<true, false, false, false, false, true, false><<<dim3(1024, 3), 256, 0, stream>>>(
      mid, mlp2w, mlp2b, nullptr, nullptr, nullptr, tok, 180, 360);
  k_final<<<65536, 64, 0, stream>>>(tok, x, upw, upb, maskp, sr);
}

// Round 2
// 737.550 us; speedup vs baseline: 1.8311x; 1.8311x over previous
//
#include <hip/hip_runtime.h>
#include <hip/hip_bf16.h>
#include <cstdint>

typedef __hip_bfloat16 bf16;
typedef __attribute__((ext_vector_type(8))) short short8;
typedef __attribute__((ext_vector_type(4))) float f32x4;

__device__ __forceinline__ float bf2f(bf16 v) { return __bfloat162float(v); }
__device__ __forceinline__ bf16  f2bf(float v) { return __float2bfloat16(v); }

// window-order row m -> token index (t*4096 + p)
__device__ __forceinline__ int win_to_token(int m) {
  int n = m >> 8, l = m & 255;
  int t = n >> 4, win = n & 15;
  int wi = win >> 2, wj = win & 3;
  int u = l >> 4, v = l & 15;
  return (t << 12) | ((wi * 16 + u) << 6) | (wj * 16 + v);
}

// ---------------- kernel 1: pool + selector MLP + gumbel mask ----------------
__global__ __launch_bounds__(64) void k_selector(
    const float* __restrict__ x, const float* __restrict__ gu,
    const float* __restrict__ s1w, const float* __restrict__ s1b,
    const float* __restrict__ s2w, const float* __restrict__ s2b,
    const float* __restrict__ s3w, const float* __restrict__ s3b,
    float* __restrict__ f1o, float* __restrict__ f2o, float* __restrict__ f3o,
    float* __restrict__ maskp) {
  int t = blockIdx.x, lane = threadIdx.x;
  int th = t >> 2, tw = t & 3;
  __shared__ float pooled[192];
  __shared__ float f1s[64], f2s[32], f3s[2];
  for (int o = lane; o < 192; o += 64) {
    int ch = o % 3, j = (o / 3) & 7, i = o / 24;
    const float* xp = x + ch * 65536 + (th * 64 + i * 8) * 256 + (tw * 64 + j * 8);
    float s = 0.f;
    for (int a = 0; a < 8; ++a)
      for (int b = 0; b < 8; ++b) s += xp[a * 256 + b];
    pooled[o] = s * (1.0f / 64.0f);
  }
  __syncthreads();
  {
    float s = s1b[lane];
    for (int k = 0; k < 192; ++k) s = fmaf(pooled[k], s1w[k * 64 + lane], s);
    f1o[t * 64 + lane] = s;
    f1s[lane] = fmaxf(s, 0.f);
  }
  __syncthreads();
  if (lane < 32) {
    float s = s2b[lane];
    for (int k = 0; k < 64; ++k) s = fmaf(f1s[k], s2w[k * 32 + lane], s);
    f2o[t * 32 + lane] = s;
    f2s[lane] = fmaxf(s, 0.f);
  }
  __syncthreads();
  if (lane < 2) {
    float s = s3b[lane];
    for (int k = 0; k < 32; ++k) s = fmaf(f2s[k], s3w[k * 2 + lane], s);
    f3o[t * 2 + lane] = s;
    f3s[lane] = s;
  }
  __syncthreads();
  if (lane == 0) {
    float g0 = -logf(-logf(gu[t * 2 + 0] + 1e-10f) + 1e-10f);
    float g1 = -logf(-logf(gu[t * 2 + 1] + 1e-10f) + 1e-10f);
    maskp[t] = (f3s[1] + g1 > f3s[0] + g0) ? 1.0f : 0.0f;
  }
}

// ---------------- embed (3->180) + LN1 applied, outputs window-major ----------------
__global__ __launch_bounds__(256) void k_embed(
    const float* __restrict__ x, const float* __restrict__ ew,
    const float* __restrict__ eb, const float* __restrict__ g1,
    const float* __restrict__ b1, bf16* __restrict__ tok,
    bf16* __restrict__ Aq) {
  int wrow = blockIdx.x * 4 + (threadIdx.x >> 6);
  int lane = threadIdx.x & 63;
  int token = win_to_token(wrow);
  int t = token >> 12, p = token & 4095;
  int r = p >> 6, c = p & 63;
  int gh = (t >> 2) * 64 + r, gw = (t & 3) * 64 + c;
  float x0 = x[gh * 256 + gw];
  float x1 = x[65536 + gh * 256 + gw];
  float x2 = x[131072 + gh * 256 + gw];
  float v[3];
  float s = 0.f, s2 = 0.f;
#pragma unroll
  for (int i = 0; i < 3; ++i) {
    int e = lane + i * 64;
    float vv = 0.f;
    if (e < 180) {
      vv = eb[e];
      vv = fmaf(x0, ew[e], vv);
      vv = fmaf(x1, ew[180 + e], vv);
      vv = fmaf(x2, ew[360 + e], vv);
      tok[(size_t)wrow * 180 + e] = f2bf(vv);
      s += vv; s2 = fmaf(vv, vv, s2);
    }
    v[i] = vv;
  }
#pragma unroll
  for (int off = 32; off; off >>= 1) { s += __shfl_xor(s, off); s2 += __shfl_xor(s2, off); }
  float mu = s * (1.f / 180.f);
  float rs = rsqrtf(s2 * (1.f / 180.f) - mu * mu + 1e-5f);
#pragma unroll
  for (int i = 0; i < 3; ++i) {
    int e = lane + i * 64;
    if (e < 192) {
      float a = (e < 180) ? ((v[i] - mu) * rs * g1[e] + b1[e]) : 0.f;
      Aq[(size_t)wrow * 192 + e] = f2bf(a);
    }
  }
}

// ---------------- LN2 prep: read tok bf16, write LN2'd bf16 A (padded 192) ----------------
__global__ __launch_bounds__(256) void k_ln2prep(
    const bf16* __restrict__ tok, const float* __restrict__ g2,
    const float* __restrict__ b2, bf16* __restrict__ A2) {
  int wrow = blockIdx.x * 4 + (threadIdx.x >> 6);
  int lane = threadIdx.x & 63;
  float v[3];
  float s = 0.f, s2 = 0.f;
#pragma unroll
  for (int i = 0; i < 3; ++i) {
    int e = lane + i * 64;
    float vv = 0.f;
    if (e < 180) {
      vv = bf2f(tok[(size_t)wrow * 180 + e]);
      s += vv; s2 = fmaf(vv, vv, s2);
    }
    v[i] = vv;
  }
#pragma unroll
  for (int off = 32; off; off >>= 1) { s += __shfl_xor(s, off); s2 += __shfl_xor(s2, off); }
  float mu = s * (1.f / 180.f);
  float rs = rsqrtf(s2 * (1.f / 180.f) - mu * mu + 1e-5f);
#pragma unroll
  for (int i = 0; i < 3; ++i) {
    int e = lane + i * 64;
    if (e < 192) {
      float a = (e < 180) ? ((v[i] - mu) * rs * g2[e] + b2[e]) : 0.f;
      A2[(size_t)wrow * 192 + e] = f2bf(a);
    }
  }
}

// ---------------- MFMA GEMM: C[65536 x N] = A[.,K]*B[K,N] (+bias, gelu, accum) ----------
// A bf16 row-major (ldA, K-padded with zeros). B fp32 global, staged to LDS transposed.
// block: 256 thr / 4 waves; tile 128 rows x 64 cols; wave: 32 rows -> acc[2][4] frags.
template <int KPAD, bool GELU_E, bool ACCUM, bool PADC>
__global__ __launch_bounds__(256) void k_mfma_gemm(
    const bf16* __restrict__ A, int ldA,
    const float* __restrict__ Bw, const float* __restrict__ bias,
    bf16* __restrict__ Cp, int ldC, int N, int K) {
  constexpr int KP = KPAD + 8;  // LDS row stride (bf16): 16B-aligned rows, 2-way banks
  __shared__ bf16 Bs[64][KP];
  const int tid = threadIdx.x;
  const int n0 = blockIdx.x * 64;
  const int m0 = blockIdx.y * 128;
  // stage B (transposed: Bs[n_local][k]), zero-pad k>=K and n>=N
  for (int flat = tid; flat < KPAD * 64; flat += 256) {
    int k = flat >> 6, nl = flat & 63;
    float v = 0.f;
    if (k < K && (n0 + nl) < N) v = Bw[(size_t)k * N + (n0 + nl)];
    Bs[nl][k] = f2bf(v);
  }
  __syncthreads();
  const int w = tid >> 6, l = tid & 63;
  const int lr = l & 15, lk = l >> 4;
  f32x4 acc[2][4];
#pragma unroll
  for (int i = 0; i < 2; ++i)
#pragma unroll
    for (int j = 0; j < 4; ++j) acc[i][j] = (f32x4){0.f, 0.f, 0.f, 0.f};
  const bf16* Arow = A + (size_t)(m0 + w * 32 + lr) * ldA + lk * 8;
#pragma unroll
  for (int ks = 0; ks < KPAD / 32; ++ks) {
    short8 fa[2], fb[4];
#pragma unroll
    for (int i = 0; i < 2; ++i)
      fa[i] = *(const short8*)(Arow + (size_t)i * 16 * ldA + ks * 32);
#pragma unroll
    for (int j = 0; j < 4; ++j)
      fb[j] = *(const short8*)(&Bs[j * 16 + lr][ks * 32 + lk * 8]);
#pragma unroll
    for (int i = 0; i < 2; ++i)
#pragma unroll
      for (int j = 0; j < 4; ++j)
        acc[i][j] = __builtin_amdgcn_mfma_f32_16x16x32_bf16(fa[i], fb[j], acc[i][j], 0, 0, 0);
  }
  // epilogue: C row = m0+w*32+i*16+lk*4+q, col = n0+j*16+lr
#pragma unroll
  for (int i = 0; i < 2; ++i) {
    int mbase = m0 + w * 32 + i * 16 + lk * 4;
#pragma unroll
    for (int j = 0; j < 4; ++j) {
      int n = n0 + j * 16 + lr;
      bool valid = n < N;
      if (!valid && !PADC) continue;
      if (n >= ldC) continue;
#pragma unroll
      for (int q = 0; q < 4; ++q) {
        int m = mbase + q;
        bf16* cp = Cp + (size_t)m * ldC + n;
        float vv = 0.f;
        if (valid) {
          vv = acc[i][j][q] + bias[n];
          if (GELU_E) {
            float u = 0.7978845608028654f * (vv + 0.044715f * vv * vv * vv);
            vv = vv / (1.f + __expf(-2.f * u));  // v * sigmoid(2u) = v*0.5*(1+tanh(u))
          }
        }
        if (ACCUM) vv += bf2f(*cp);
        *cp = f2bf(vv);
      }
    }
  }
}

// ---------------- attention: one block per (window, head), thread = query row ----------------
__global__ __launch_bounds__(256) void k_attn(const bf16* __restrict__ qkv,
                                              bf16* __restrict__ av) {
  int blk = blockIdx.x;
  int n = blk / 6, hd = blk % 6;
  int l = threadIdx.x;
  const float scale = 0.18257418583505536f;  // 1/sqrt(30)
  float q[30];
  const bf16* qrow = qkv + ((size_t)n * 256 + l) * 540 + hd * 30;
#pragma unroll
  for (int d = 0; d < 30; ++d) q[d] = bf2f(qrow[d]) * scale;
  __shared__ float ks[64][32];
  __shared__ float vs[64][32];
  float m_run = -1e30f, l_run = 0.f;
  float acc[30];
#pragma unroll
  for (int d = 0; d < 30; ++d) acc[d] = 0.f;
  for (int mt = 0; mt < 256; mt += 64) {
    __syncthreads();
    for (int idx = threadIdx.x; idx < 64 * 30; idx += 256) {
      int row = idx / 30, d = idx % 30;
      const bf16* base = qkv + ((size_t)n * 256 + mt + row) * 540 + hd * 30;
      ks[row][d] = bf2f(base[180 + d]);
      vs[row][d] = bf2f(base[360 + d]);
    }
    __syncthreads();
    for (int mm = 0; mm < 64; ++mm) {
      float s = 0.f;
#pragma unroll
      for (int d = 0; d < 30; ++d) s = fmaf(q[d], ks[mm][d], s);
      float mnew = fmaxf(m_run, s);
      float corr = __expf(m_run - mnew);
      float p = __expf(s - mnew);
      l_run = fmaf(l_run, corr, p);
#pragma unroll
      for (int d = 0; d < 30; ++d) acc[d] = fmaf(acc[d], corr, p * vs[mm][d]);
      m_run = mnew;
    }
  }
  float inv = 1.f / l_run;
  bf16* out = av + ((size_t)n * 256 + l) * 192 + hd * 30;
#pragma unroll
  for (int d = 0; d < 30; ++d) out[d] = f2bf(acc[d] * inv);
  if (hd == 0) {
    bf16* pr = av + ((size_t)n * 256 + l) * 192 + 180;
#pragma unroll
    for (int d = 0; d < 12; ++d) pr[d] = f2bf(0.f);
  }
}

// ---------------- bicubic weights (jax Keys a=-0.5, half-pixel, edge renorm) ----------------
__device__ const float c_cubw[4][4] = {
    {-0.0439453125f, 0.3896484375f, 0.7275390625f, -0.0732421875f},  // phase 0: taps r-2..r+1
    {-0.0068359375f, 0.0908203125f, 0.9638671875f, -0.0478515625f},  // phase 1: taps r-2..r+1
    {-0.0478515625f, 0.9638671875f, 0.0908203125f, -0.0068359375f},  // phase 2: taps r-1..r+2
    {-0.0732421875f, 0.7275390625f, 0.3896484375f, -0.0439453125f},  // phase 3: taps r-1..r+2
};

__device__ __forceinline__ void cubw(int r, int ph, float* w, int& base) {
  base = r + ((ph < 2) ? -2 : -1);
  float sum = 0.f;
#pragma unroll
  for (int i = 0; i < 4; ++i) {
    int idx = base + i;
    float wi = (idx >= 0 && idx < 64) ? c_cubw[ph][i] : 0.f;
    w[i] = wi; sum += wi;
  }
  float inv = 1.f / sum;
#pragma unroll
  for (int i = 0; i < 4; ++i) w[i] *= inv;
}

// ---------------- final: up-proj + pixel shuffle + bicubic + blend ----------------
__global__ __launch_bounds__(64) void k_final(
    const bf16* __restrict__ tok, const float* __restrict__ x,
    const float* __restrict__ upw, const float* __restrict__ upb,
    const float* __restrict__ maskp, float* __restrict__ sr) {
  int wrow = blockIdx.x;
  int lane = threadIdx.x;
  int token = win_to_token(wrow);
  int t = token >> 12, p = token & 4095;
  int r = p >> 6, c = p & 63;
  int th = t >> 2, tw = t & 3;
  __shared__ float trow[180];
  for (int e = lane; e < 180; e += 64) trow[e] = bf2f(tok[(size_t)wrow * 180 + e]);
  __syncthreads();
  if (lane >= 48) return;
  int e = lane;
  float s = upb[e];
  for (int k = 0; k < 180; ++k) s = fmaf(trow[k], upw[k * 48 + e], s);
  int ch = e % 3, b = (e / 3) & 3, a = e / 12;
  float wy[4], wx[4];
  int yb, xb;
  cubw(r, a, wy, yb);
  cubw(c, b, wx, xb);
  const float* xc = x + ch * 65536;
  float neg = 0.f;
#pragma unroll
  for (int i = 0; i < 4; ++i) {
    int yi = yb + i;
    if (yi < 0 || yi > 63) continue;
    float rowsum = 0.f;
#pragma unroll
    for (int j = 0; j < 4; ++j) {
      int xj = xb + j;
      if (xj < 0 || xj > 63) continue;
      rowsum = fmaf(wx[j], xc[(th * 64 + yi) * 256 + tw * 64 + xj], rowsum);
    }
    neg = fmaf(wy[i], rowsum, neg);
  }
  float m = maskp[t];
  float outv = m * s + (1.f - m) * neg;
  int R = r * 4 + a, C = c * 4 + b;
  sr[(size_t)ch * 1048576 + (size_t)(th * 256 + R) * 1024 + (tw * 256 + C)] = outv;
}

// ---------------- launcher ----------------
extern "C" void kernel_launch(void* const* d_in, const int* in_sizes, int n_in,
                              void* d_out, int out_size, void* d_ws, size_t ws_size,
                              hipStream_t stream) {
  const float* x     = (const float*)d_in[0];
  const float* gu    = (const float*)d_in[1];
  const float* s1w   = (const float*)d_in[2];
  const float* s1b   = (const float*)d_in[3];
  const float* s2w   = (const float*)d_in[4];
  const float* s2b   = (const float*)d_in[5];
  const float* s3w   = (const float*)d_in[6];
  const float* s3b   = (const float*)d_in[7];
  const float* ew    = (const float*)d_in[8];
  const float* ebias = (const float*)d_in[9];
  const float* ln1g  = (const float*)d_in[10];
  const float* ln1b  = (const float*)d_in[11];
  const float* qkvw  = (const float*)d_in[12];
  const float* qkvb  = (const float*)d_in[13];
  const float* projw = (const float*)d_in[14];
  const float* projb = (const float*)d_in[15];
  const float* ln2g  = (const float*)d_in[16];
  const float* ln2b  = (const float*)d_in[17];
  const float* mlp1w = (const float*)d_in[18];
  const float* mlp1b = (const float*)d_in[19];
  const float* mlp2w = (const float*)d_in[20];
  const float* mlp2b = (const float*)d_in[21];
  const float* upw   = (const float*)d_in[22];
  const float* upb   = (const float*)d_in[23];

  float* out = (float*)d_out;
  float* sr  = out;                 // 3*1024*1024
  float* f3o = out + 3145728;       // 16*2
  float* f2o = f3o + 32;            // 16*32
  float* f1o = f2o + 512;           // 16*64

  char* ws = (char*)d_ws;
  bf16* tok  = (bf16*)(ws);                  // 65536*180 bf16 = 23,592,960 B
  bf16* ABuf = (bf16*)(ws + 23592960);       // 65536*192 bf16 = 25,165,824 B (Aq -> avb -> A2)
  bf16* big  = (bf16*)(ws + 48758784);       // 65536*540 bf16 = 70,778,880 B (qkv -> mid)
  float* maskp = (float*)(ws + 119537664);   // 16 fp32

  bf16* qkv = big;       // [65536][540]
  bf16* mid = big;       // [65536][384]

  k_selector<<<16, 64, 0, stream>>>(x, gu, s1w, s1b, s2w, s2b, s3w, s3b, f1o, f2o, f3o, maskp);
  k_embed<<<16384, 256, 0, stream>>>(x, ew, ebias, ln1g, ln1b, tok, ABuf);
  // qkv = LN1(tok) @ qkv_w + qkv_b
  k_mfma_gemm<192, false, false, false><<<dim3(9, 512), 256, 0, stream>>>(
      ABuf, 192, qkvw, qkvb, qkv, 540, 540, 180);
  k_attn<<<1536, 256, 0, stream>>>(qkv, ABuf);
  // tok += av @ proj_w + proj_b
  k_mfma_gemm<192, false, true, false><<<dim3(3, 512), 256, 0, stream>>>(
      ABuf, 192, projw, projb, tok, 180, 180, 180);
  k_ln2prep<<<16384, 256, 0, stream>>>(tok, ln2g, ln2b, ABuf);
  // mid = gelu(LN2(tok) @ mlp1_w + mlp1_b), zero-padded to 384 cols
  k_mfma_gemm<192, true, false, true><<<dim3(6, 512), 256, 0, stream>>>(
      ABuf, 192, mlp1w, mlp1b, mid, 384, 360, 180);
  // tok += mid @ mlp2_w + mlp2_b
  k_mfma_gemm<384, false, true, false><<<dim3(3, 512), 256, 0, stream>>>(
      mid, 384, mlp2w, mlp2b, tok, 180, 180, 360);
  k_final<<<65536, 64, 0, stream>>>(tok, x, upw, upb, maskp, sr);
}

// Round 3
// 585.253 us; speedup vs baseline: 2.3076x; 1.2602x over previous
//
#include <hip/hip_runtime.h>
#include <hip/hip_bf16.h>
#include <cstdint>

typedef __hip_bfloat16 bf16;
typedef __attribute__((ext_vector_type(8))) short short8;
typedef __attribute__((ext_vector_type(4))) float f32x4;

__device__ __forceinline__ float bf2f(bf16 v) { return __bfloat162float(v); }
__device__ __forceinline__ bf16  f2bf(float v) { return __float2bfloat16(v); }
__device__ __forceinline__ uint32_t pack2(float a, float b) {
  bf16 x = f2bf(a), y = f2bf(b);
  uint16_t xa = *(uint16_t*)&x, ya = *(uint16_t*)&y;
  return (uint32_t)xa | ((uint32_t)ya << 16);
}

// window-order row m -> token index (t*4096 + p)
__device__ __forceinline__ int win_to_token(int m) {
  int n = m >> 8, l = m & 255;
  int t = n >> 4, win = n & 15;
  int wi = win >> 2, wj = win & 3;
  int u = l >> 4, v = l & 15;
  return (t << 12) | ((wi * 16 + u) << 6) | (wj * 16 + v);
}

// ---------------- kernel 1: pool + selector MLP + gumbel mask ----------------
__global__ __launch_bounds__(64) void k_selector(
    const float* __restrict__ x, const float* __restrict__ gu,
    const float* __restrict__ s1w, const float* __restrict__ s1b,
    const float* __restrict__ s2w, const float* __restrict__ s2b,
    const float* __restrict__ s3w, const float* __restrict__ s3b,
    float* __restrict__ f1o, float* __restrict__ f2o, float* __restrict__ f3o,
    float* __restrict__ maskp) {
  int t = blockIdx.x, lane = threadIdx.x;
  int th = t >> 2, tw = t & 3;
  __shared__ float pooled[192];
  __shared__ float f1s[64], f2s[32], f3s[2];
  for (int o = lane; o < 192; o += 64) {
    int ch = o % 3, j = (o / 3) & 7, i = o / 24;
    const float* xp = x + ch * 65536 + (th * 64 + i * 8) * 256 + (tw * 64 + j * 8);
    float s = 0.f;
    for (int a = 0; a < 8; ++a)
      for (int b = 0; b < 8; ++b) s += xp[a * 256 + b];
    pooled[o] = s * (1.0f / 64.0f);
  }
  __syncthreads();
  {
    float s = s1b[lane];
    for (int k = 0; k < 192; ++k) s = fmaf(pooled[k], s1w[k * 64 + lane], s);
    f1o[t * 64 + lane] = s;
    f1s[lane] = fmaxf(s, 0.f);
  }
  __syncthreads();
  if (lane < 32) {
    float s = s2b[lane];
    for (int k = 0; k < 64; ++k) s = fmaf(f1s[k], s2w[k * 32 + lane], s);
    f2o[t * 32 + lane] = s;
    f2s[lane] = fmaxf(s, 0.f);
  }
  __syncthreads();
  if (lane < 2) {
    float s = s3b[lane];
    for (int k = 0; k < 32; ++k) s = fmaf(f2s[k], s3w[k * 2 + lane], s);
    f3o[t * 2 + lane] = s;
    f3s[lane] = s;
  }
  __syncthreads();
  if (lane == 0) {
    float g0 = -logf(-logf(gu[t * 2 + 0] + 1e-10f) + 1e-10f);
    float g1 = -logf(-logf(gu[t * 2 + 1] + 1e-10f) + 1e-10f);
    maskp[t] = (f3s[1] + g1 > f3s[0] + g0) ? 1.0f : 0.0f;
  }
}

// ---------------- embed (3->180) + LN1 applied, outputs window-major ----------------
__global__ __launch_bounds__(256) void k_embed(
    const float* __restrict__ x, const float* __restrict__ ew,
    const float* __restrict__ eb, const float* __restrict__ g1,
    const float* __restrict__ b1, bf16* __restrict__ tok,
    bf16* __restrict__ Aq) {
  int wrow = blockIdx.x * 4 + (threadIdx.x >> 6);
  int lane = threadIdx.x & 63;
  int token = win_to_token(wrow);
  int t = token >> 12, p = token & 4095;
  int r = p >> 6, c = p & 63;
  int gh = (t >> 2) * 64 + r, gw = (t & 3) * 64 + c;
  float x0 = x[gh * 256 + gw];
  float x1 = x[65536 + gh * 256 + gw];
  float x2 = x[131072 + gh * 256 + gw];
  float v[3];
  float s = 0.f, s2 = 0.f;
#pragma unroll
  for (int i = 0; i < 3; ++i) {
    int e = lane + i * 64;
    float vv = 0.f;
    if (e < 180) {
      vv = eb[e];
      vv = fmaf(x0, ew[e], vv);
      vv = fmaf(x1, ew[180 + e], vv);
      vv = fmaf(x2, ew[360 + e], vv);
      tok[(size_t)wrow * 180 + e] = f2bf(vv);
      s += vv; s2 = fmaf(vv, vv, s2);
    }
    v[i] = vv;
  }
#pragma unroll
  for (int off = 32; off; off >>= 1) { s += __shfl_xor(s, off); s2 += __shfl_xor(s2, off); }
  float mu = s * (1.f / 180.f);
  float rs = rsqrtf(s2 * (1.f / 180.f) - mu * mu + 1e-5f);
#pragma unroll
  for (int i = 0; i < 3; ++i) {
    int e = lane + i * 64;
    if (e < 192) {
      float a = (e < 180) ? ((v[i] - mu) * rs * g1[e] + b1[e]) : 0.f;
      Aq[(size_t)wrow * 192 + e] = f2bf(a);
    }
  }
}

// ---------------- LN2 prep: read tok bf16, write LN2'd bf16 A (padded 192) ----------------
__global__ __launch_bounds__(256) void k_ln2prep(
    const bf16* __restrict__ tok, const float* __restrict__ g2,
    const float* __restrict__ b2, bf16* __restrict__ A2) {
  int wrow = blockIdx.x * 4 + (threadIdx.x >> 6);
  int lane = threadIdx.x & 63;
  float v[3];
  float s = 0.f, s2 = 0.f;
#pragma unroll
  for (int i = 0; i < 3; ++i) {
    int e = lane + i * 64;
    float vv = 0.f;
    if (e < 180) {
      vv = bf2f(tok[(size_t)wrow * 180 + e]);
      s += vv; s2 = fmaf(vv, vv, s2);
    }
    v[i] = vv;
  }
#pragma unroll
  for (int off = 32; off; off >>= 1) { s += __shfl_xor(s, off); s2 += __shfl_xor(s2, off); }
  float mu = s * (1.f / 180.f);
  float rs = rsqrtf(s2 * (1.f / 180.f) - mu * mu + 1e-5f);
#pragma unroll
  for (int i = 0; i < 3; ++i) {
    int e = lane + i * 64;
    if (e < 192) {
      float a = (e < 180) ? ((v[i] - mu) * rs * g2[e] + b2[e]) : 0.f;
      A2[(size_t)wrow * 192 + e] = f2bf(a);
    }
  }
}

// ---------------- zero head-pad cols (d=30,31) of Qp/Kp ----------------
__global__ __launch_bounds__(256) void k_padzero(bf16* __restrict__ Qp,
                                                 bf16* __restrict__ Kp) {
  int row = blockIdx.x * 256 + threadIdx.x;
#pragma unroll
  for (int hd = 0; hd < 6; ++hd) {
    *(uint32_t*)&Qp[(size_t)row * 192 + hd * 32 + 30] = 0;
    *(uint32_t*)&Kp[(size_t)row * 192 + hd * 32 + 30] = 0;
  }
}

// ---------------- MFMA GEMM: C[65536 x N] = A[.,K]*B[K,N] ----------
// EPI: 0=plain store, 1=accum into C, 2=gelu+pad store, 3=QKV split
template <int KPAD, int EPI>
__global__ __launch_bounds__(256) void k_mfma_gemm(
    const bf16* __restrict__ A, int ldA,
    const float* __restrict__ Bw, const float* __restrict__ bias,
    bf16* __restrict__ Cp, int ldC, int N, int K,
    bf16* __restrict__ Qo, bf16* __restrict__ Ko, bf16* __restrict__ Vo) {
  constexpr int KP = KPAD + 8;
  __shared__ bf16 Bs[64][KP];
  const int tid = threadIdx.x;
  const int n0 = blockIdx.x * 64;
  const int m0 = blockIdx.y * 128;
  for (int flat = tid; flat < KPAD * 64; flat += 256) {
    int k = flat >> 6, nl = flat & 63;
    float v = 0.f;
    if (k < K && (n0 + nl) < N) v = Bw[(size_t)k * N + (n0 + nl)];
    Bs[nl][k] = f2bf(v);
  }
  __syncthreads();
  const int w = tid >> 6, l = tid & 63;
  const int lr = l & 15, lk = l >> 4;
  f32x4 acc[2][4];
#pragma unroll
  for (int i = 0; i < 2; ++i)
#pragma unroll
    for (int j = 0; j < 4; ++j) acc[i][j] = (f32x4){0.f, 0.f, 0.f, 0.f};
  const bf16* Arow = A + (size_t)(m0 + w * 32 + lr) * ldA + lk * 8;
#pragma unroll
  for (int ks = 0; ks < KPAD / 32; ++ks) {
    short8 fa[2], fb[4];
#pragma unroll
    for (int i = 0; i < 2; ++i)
      fa[i] = *(const short8*)(Arow + (size_t)i * 16 * ldA + ks * 32);
#pragma unroll
    for (int j = 0; j < 4; ++j)
      fb[j] = *(const short8*)(&Bs[j * 16 + lr][ks * 32 + lk * 8]);
#pragma unroll
    for (int i = 0; i < 2; ++i)
#pragma unroll
      for (int j = 0; j < 4; ++j)
        acc[i][j] = __builtin_amdgcn_mfma_f32_16x16x32_bf16(fa[i], fb[j], acc[i][j], 0, 0, 0);
  }
#pragma unroll
  for (int i = 0; i < 2; ++i) {
    int mbase = m0 + w * 32 + i * 16 + lk * 4;
#pragma unroll
    for (int j = 0; j < 4; ++j) {
      int n = n0 + j * 16 + lr;
#pragma unroll
      for (int q = 0; q < 4; ++q) {
        int m = mbase + q;
        if (n >= N) {
          if (EPI == 2 && n < ldC) Cp[(size_t)m * ldC + n] = f2bf(0.f);
          continue;
        }
        float vv = acc[i][j][q] + bias[n];
        if (EPI == 2) {
          float u = 0.7978845608028654f * (vv + 0.044715f * vv * vv * vv);
          vv = vv / (1.f + __expf(-2.f * u));
        }
        if (EPI == 3) {
          int buf = n / 180, dp = n % 180;
          int hd = dp / 30, dd = dp % 30;
          int colp = hd * 32 + dd;
          if (buf == 0)      Qo[(size_t)m * 192 + colp] = f2bf(vv);
          else if (buf == 1) Ko[(size_t)m * 192 + colp] = f2bf(vv);
          else               Vo[(size_t)colp * 65536 + m] = f2bf(vv);
        } else {
          bf16* cp = Cp + (size_t)m * ldC + n;
          if (EPI == 1) vv += bf2f(*cp);
          *cp = f2bf(vv);
        }
      }
    }
  }
}

// ---------------- MFMA attention: block = (window, head), 4 waves ----------------
__global__ __launch_bounds__(256) void k_attn_mfma(
    const bf16* __restrict__ Qp, const bf16* __restrict__ Kp,
    const bf16* __restrict__ Vt, bf16* __restrict__ av) {
  const int blk = blockIdx.x;
  const int win = blk / 6, hd = blk % 6;
  const int tid = threadIdx.x;
  const int w = tid >> 6, l = tid & 63;
  const int lr = l & 15, lk = l >> 4;
  const float scale = 0.18257418583505536f;  // 1/sqrt(30)

  __shared__ bf16 Ks[256][40];     // keys x d(32, stride 40)
  __shared__ bf16 Vs[32][264];     // d x keys (stride 264)
  __shared__ bf16 Ps[4][16][264];  // per-wave P: q x keys

  // stage K: thread t -> key row t, 32 bf16 = 4x16B
  {
    const bf16* src = Kp + (size_t)(win * 256 + tid) * 192 + hd * 32;
#pragma unroll
    for (int c = 0; c < 4; ++c)
      *(short8*)&Ks[tid][c * 8] = *(const short8*)(src + c * 8);
  }
  // stage V^T: thread t -> d = t>>3, keys (t&7)*32..+31
  {
    int d = tid >> 3, ck = tid & 7;
    const bf16* src = Vt + (size_t)(hd * 32 + d) * 65536 + win * 256 + ck * 32;
#pragma unroll
    for (int c = 0; c < 4; ++c)
      *(short8*)&Vs[d][ck * 32 + c * 8] = *(const short8*)(src + c * 8);
  }
  __syncthreads();

  for (int qt = 0; qt < 4; ++qt) {
    const int qbase = qt * 64 + w * 16;
    // Q B-frag: n=lr (query), k-slice lk*8
    short8 fq = *(const short8*)(Qp + (size_t)(win * 256 + qbase + lr) * 192 + hd * 32 + lk * 8);
    // S^T = K @ Q^T : 16 key-tiles
    f32x4 accS[16];
#pragma unroll
    for (int kt = 0; kt < 16; ++kt) {
      short8 fk = *(const short8*)(&Ks[kt * 16 + lr][lk * 8]);
      accS[kt] = __builtin_amdgcn_mfma_f32_16x16x32_bf16(
          fk, fq, (f32x4){0.f, 0.f, 0.f, 0.f}, 0, 0, 0);
    }
    // row softmax: lane has query q=qbase+lr, keys kt*16+lk*4+r
    float mraw = -1e30f;
#pragma unroll
    for (int kt = 0; kt < 16; ++kt)
#pragma unroll
      for (int r = 0; r < 4; ++r) mraw = fmaxf(mraw, accS[kt][r]);
    mraw = fmaxf(mraw, __shfl_xor(mraw, 16));
    mraw = fmaxf(mraw, __shfl_xor(mraw, 32));
    const float mc = mraw * scale;
    float lsum = 0.f;
#pragma unroll
    for (int kt = 0; kt < 16; ++kt) {
      float p0 = __expf(fmaf(accS[kt][0], scale, -mc));
      float p1 = __expf(fmaf(accS[kt][1], scale, -mc));
      float p2 = __expf(fmaf(accS[kt][2], scale, -mc));
      float p3 = __expf(fmaf(accS[kt][3], scale, -mc));
      lsum += (p0 + p1) + (p2 + p3);
      uint32_t d0 = pack2(p0, p1), d1 = pack2(p2, p3);
      *(uint32_t*)&Ps[w][lr][kt * 16 + lk * 4]     = d0;
      *(uint32_t*)&Ps[w][lr][kt * 16 + lk * 4 + 2] = d1;
    }
    lsum += __shfl_xor(lsum, 16);
    lsum += __shfl_xor(lsum, 32);
    __syncthreads();
    // PV: O[q][d] = P[q][keys] @ V[keys][d]
    f32x4 accO0 = (f32x4){0.f, 0.f, 0.f, 0.f};
    f32x4 accO1 = (f32x4){0.f, 0.f, 0.f, 0.f};
#pragma unroll
    for (int ks = 0; ks < 8; ++ks) {
      short8 fp = *(const short8*)(&Ps[w][lr][ks * 32 + lk * 8]);
      short8 fv0 = *(const short8*)(&Vs[lr][ks * 32 + lk * 8]);
      short8 fv1 = *(const short8*)(&Vs[16 + lr][ks * 32 + lk * 8]);
      accO0 = __builtin_amdgcn_mfma_f32_16x16x32_bf16(fp, fv0, accO0, 0, 0, 0);
      accO1 = __builtin_amdgcn_mfma_f32_16x16x32_bf16(fp, fv1, accO1, 0, 0, 0);
    }
    // normalize + store: lane holds d = dt*16+lr, rows q = qbase+lk*4+r
    float invl = 1.f / lsum;
#pragma unroll
    for (int r = 0; r < 4; ++r) {
      float inv_r = __shfl(invl, lk * 4 + r);
      int row = win * 256 + qbase + lk * 4 + r;
      int d0 = lr, d1 = 16 + lr;
      if (d0 < 30) av[(size_t)row * 192 + hd * 30 + d0] = f2bf(accO0[r] * inv_r);
      if (d1 < 30) av[(size_t)row * 192 + hd * 30 + d1] = f2bf(accO1[r] * inv_r);
      if (hd == 0 && lr < 12) av[(size_t)row * 192 + 180 + lr] = f2bf(0.f);
    }
    __syncthreads();
  }
}

// ---------------- bicubic weights (jax Keys a=-0.5, half-pixel, edge renorm) ----------------
__device__ const float c_cubw[4][4] = {
    {-0.0439453125f, 0.3896484375f, 0.7275390625f, -0.0732421875f},
    {-0.0068359375f, 0.0908203125f, 0.9638671875f, -0.0478515625f},
    {-0.0478515625f, 0.9638671875f, 0.0908203125f, -0.0068359375f},
    {-0.0732421875f, 0.7275390625f, 0.3896484375f, -0.0439453125f},
};

__device__ __forceinline__ void cubw(int r, int ph, float* w, int& base) {
  base = r + ((ph < 2) ? -2 : -1);
  float sum = 0.f;
#pragma unroll
  for (int i = 0; i < 4; ++i) {
    int idx = base + i;
    float wi = (idx >= 0 && idx < 64) ? c_cubw[ph][i] : 0.f;
    w[i] = wi; sum += wi;
  }
  float inv = 1.f / sum;
#pragma unroll
  for (int i = 0; i < 4; ++i) w[i] *= inv;
}

// ---------------- final: up-proj + pixel shuffle + bicubic + blend ----------------
__global__ __launch_bounds__(64) void k_final(
    const bf16* __restrict__ tok, const float* __restrict__ x,
    const float* __restrict__ upw, const float* __restrict__ upb,
    const float* __restrict__ maskp, float* __restrict__ sr) {
  int wrow = blockIdx.x;
  int lane = threadIdx.x;
  int token = win_to_token(wrow);
  int t = token >> 12, p = token & 4095;
  int r = p >> 6, c = p & 63;
  int th = t >> 2, tw = t & 3;
  __shared__ float trow[180];
  for (int e = lane; e < 180; e += 64) trow[e] = bf2f(tok[(size_t)wrow * 180 + e]);
  __syncthreads();
  if (lane >= 48) return;
  int e = lane;
  float s = upb[e];
  for (int k = 0; k < 180; ++k) s = fmaf(trow[k], upw[k * 48 + e], s);
  int ch = e % 3, b = (e / 3) & 3, a = e / 12;
  float wy[4], wx[4];
  int yb, xb;
  cubw(r, a, wy, yb);
  cubw(c, b, wx, xb);
  const float* xc = x + ch * 65536;
  float neg = 0.f;
#pragma unroll
  for (int i = 0; i < 4; ++i) {
    int yi = yb + i;
    if (yi < 0 || yi > 63) continue;
    float rowsum = 0.f;
#pragma unroll
    for (int j = 0; j < 4; ++j) {
      int xj = xb + j;
      if (xj < 0 || xj > 63) continue;
      rowsum = fmaf(wx[j], xc[(th * 64 + yi) * 256 + tw * 64 + xj], rowsum);
    }
    neg = fmaf(wy[i], rowsum, neg);
  }
  float m = maskp[t];
  float outv = m * s + (1.f - m) * neg;
  int R = r * 4 + a, C = c * 4 + b;
  sr[(size_t)ch * 1048576 + (size_t)(th * 256 + R) * 1024 + (tw * 256 + C)] = outv;
}

// ---------------- launcher ----------------
extern "C" void kernel_launch(void* const* d_in, const int* in_sizes, int n_in,
                              void* d_out, int out_size, void* d_ws, size_t ws_size,
                              hipStream_t stream) {
  const float* x     = (const float*)d_in[0];
  const float* gu    = (const float*)d_in[1];
  const float* s1w   = (const float*)d_in[2];
  const float* s1b   = (const float*)d_in[3];
  const float* s2w   = (const float*)d_in[4];
  const float* s2b   = (const float*)d_in[5];
  const float* s3w   = (const float*)d_in[6];
  const float* s3b   = (const float*)d_in[7];
  const float* ew    = (const float*)d_in[8];
  const float* ebias = (const float*)d_in[9];
  const float* ln1g  = (const float*)d_in[10];
  const float* ln1b  = (const float*)d_in[11];
  const float* qkvw  = (const float*)d_in[12];
  const float* qkvb  = (const float*)d_in[13];
  const float* projw = (const float*)d_in[14];
  const float* projb = (const float*)d_in[15];
  const float* ln2g  = (const float*)d_in[16];
  const float* ln2b  = (const float*)d_in[17];
  const float* mlp1w = (const float*)d_in[18];
  const float* mlp1b = (const float*)d_in[19];
  const float* mlp2w = (const float*)d_in[20];
  const float* mlp2b = (const float*)d_in[21];
  const float* upw   = (const float*)d_in[22];
  const float* upb   = (const float*)d_in[23];

  float* out = (float*)d_out;
  float* sr  = out;                 // 3*1024*1024
  float* f3o = out + 3145728;       // 16*2
  float* f2o = f3o + 32;            // 16*32
  float* f1o = f2o + 512;           // 16*64

  char* ws = (char*)d_ws;
  bf16* tok  = (bf16*)(ws);                   // 65536*180 = 23,592,960 B
  bf16* ABuf = (bf16*)(ws + 23592960);        // 65536*192 = 25,165,824 B
  bf16* Qp   = (bf16*)(ws + 48758784);        // 65536*192 = 25,165,824 B
  bf16* Kp   = (bf16*)(ws + 73924608);        // 65536*192 = 25,165,824 B
  bf16* Vt   = (bf16*)(ws + 99090432);        // 192*65536 = 25,165,824 B
  bf16* mid  = Qp;                            // reuse Qp+Kp: 65536*384 = 50,331,648 B
  float* maskp = (float*)(ws + 124256256);    // 16 fp32

  k_selector<<<16, 64, 0, stream>>>(x, gu, s1w, s1b, s2w, s2b, s3w, s3b, f1o, f2o, f3o, maskp);
  k_embed<<<16384, 256, 0, stream>>>(x, ew, ebias, ln1g, ln1b, tok, ABuf);
  k_padzero<<<256, 256, 0, stream>>>(Qp, Kp);
  // Q/K/V = LN1(tok) @ qkv_w + qkv_b, split + head-padded
  k_mfma_gemm<192, 3><<<dim3(9, 512), 256, 0, stream>>>(
      ABuf, 192, qkvw, qkvb, nullptr, 0, 540, 180, Qp, Kp, Vt);
  k_attn_mfma<<<1536, 256, 0, stream>>>(Qp, Kp, Vt, ABuf);
  // tok += av @ proj_w + proj_b
  k_mfma_gemm<192, 1><<<dim3(3, 512), 256, 0, stream>>>(
      ABuf, 192, projw, projb, tok, 180, 180, 180, nullptr, nullptr, nullptr);
  k_ln2prep<<<16384, 256, 0, stream>>>(tok, ln2g, ln2b, ABuf);
  // mid = gelu(LN2(tok) @ mlp1_w + mlp1_b), zero-padded to 384 cols
  k_mfma_gemm<192, 2><<<dim3(6, 512), 256, 0, stream>>>(
      ABuf, 192, mlp1w, mlp1b, mid, 384, 360, 180, nullptr, nullptr, nullptr);
  // tok += mid @ mlp2_w + mlp2_b
  k_mfma_gemm<384, 1><<<dim3(3, 512), 256, 0, stream>>>(
      mid, 384, mlp2w, mlp2b, tok, 180, 180, 360, nullptr, nullptr, nullptr);
  k_final<<<65536, 64, 0, stream>>>(tok, x, upw, upb, maskp, sr);
}

// Round 4
// 426.889 us; speedup vs baseline: 3.1637x; 1.3710x over previous
//
#include <hip/hip_runtime.h>
#include <hip/hip_bf16.h>
#include <cstdint>

typedef __hip_bfloat16 bf16;
typedef __attribute__((ext_vector_type(8))) short short8;
typedef __attribute__((ext_vector_type(4))) float f32x4;

__device__ __forceinline__ float bf2f(bf16 v) { return __bfloat162float(v); }
__device__ __forceinline__ bf16  f2bf(float v) { return __float2bfloat16(v); }
__device__ __forceinline__ uint32_t pack2(float a, float b) {
  bf16 x = f2bf(a), y = f2bf(b);
  uint16_t xa = *(uint16_t*)&x, ya = *(uint16_t*)&y;
  return (uint32_t)xa | ((uint32_t)ya << 16);
}

// window-order row m -> token index (t*4096 + p)
__device__ __forceinline__ int win_to_token(int m) {
  int n = m >> 8, l = m & 255;
  int t = n >> 4, win = n & 15;
  int wi = win >> 2, wj = win & 3;
  int u = l >> 4, v = l & 15;
  return (t << 12) | ((wi * 16 + u) << 6) | (wj * 16 + v);
}

// ---------------- kernel 1: pool + selector MLP + gumbel mask ----------------
__global__ __launch_bounds__(64) void k_selector(
    const float* __restrict__ x, const float* __restrict__ gu,
    const float* __restrict__ s1w, const float* __restrict__ s1b,
    const float* __restrict__ s2w, const float* __restrict__ s2b,
    const float* __restrict__ s3w, const float* __restrict__ s3b,
    float* __restrict__ f1o, float* __restrict__ f2o, float* __restrict__ f3o,
    float* __restrict__ maskp) {
  int t = blockIdx.x, lane = threadIdx.x;
  int th = t >> 2, tw = t & 3;
  __shared__ float pooled[192];
  __shared__ float f1s[64], f2s[32], f3s[2];
  for (int o = lane; o < 192; o += 64) {
    int ch = o % 3, j = (o / 3) & 7, i = o / 24;
    const float* xp = x + ch * 65536 + (th * 64 + i * 8) * 256 + (tw * 64 + j * 8);
    float s = 0.f;
    for (int a = 0; a < 8; ++a)
      for (int b = 0; b < 8; ++b) s += xp[a * 256 + b];
    pooled[o] = s * (1.0f / 64.0f);
  }
  __syncthreads();
  {
    float s = s1b[lane];
    for (int k = 0; k < 192; ++k) s = fmaf(pooled[k], s1w[k * 64 + lane], s);
    f1o[t * 64 + lane] = s;
    f1s[lane] = fmaxf(s, 0.f);
  }
  __syncthreads();
  if (lane < 32) {
    float s = s2b[lane];
    for (int k = 0; k < 64; ++k) s = fmaf(f1s[k], s2w[k * 32 + lane], s);
    f2o[t * 32 + lane] = s;
    f2s[lane] = fmaxf(s, 0.f);
  }
  __syncthreads();
  if (lane < 2) {
    float s = s3b[lane];
    for (int k = 0; k < 32; ++k) s = fmaf(f2s[k], s3w[k * 2 + lane], s);
    f3o[t * 2 + lane] = s;
    f3s[lane] = s;
  }
  __syncthreads();
  if (lane == 0) {
    float g0 = -logf(-logf(gu[t * 2 + 0] + 1e-10f) + 1e-10f);
    float g1 = -logf(-logf(gu[t * 2 + 1] + 1e-10f) + 1e-10f);
    maskp[t] = (f3s[1] + g1 > f3s[0] + g0) ? 1.0f : 0.0f;
  }
}

// ---------------- pack all weights to bf16 Bt[n][k] (transposed, padded) ----------------
// segments: qkv 576x192, proj 192x192, mlp1 384x192, mlp2 192x384, up 64x192
__global__ __launch_bounds__(256) void k_packB(
    const float* __restrict__ qkvw, const float* __restrict__ projw,
    const float* __restrict__ mlp1w, const float* __restrict__ mlp2w,
    const float* __restrict__ upw, bf16* __restrict__ Bt_qkv,
    bf16* __restrict__ Bt_proj, bf16* __restrict__ Bt_mlp1,
    bf16* __restrict__ Bt_mlp2, bf16* __restrict__ Bt_up) {
  int idx = blockIdx.x * 256 + threadIdx.x;
  // seg boundaries (elements)
  const int e0 = 576 * 192, e1 = e0 + 192 * 192, e2 = e1 + 384 * 192,
            e3 = e2 + 192 * 384, e4 = e3 + 64 * 192;
  const float* src; bf16* dst; int K, N, KP, base;
  if (idx < e0)      { src = qkvw;  dst = Bt_qkv;  K = 180; N = 540; KP = 192; base = 0; }
  else if (idx < e1) { src = projw; dst = Bt_proj; K = 180; N = 180; KP = 192; base = e0; }
  else if (idx < e2) { src = mlp1w; dst = Bt_mlp1; K = 180; N = 360; KP = 192; base = e1; }
  else if (idx < e3) { src = mlp2w; dst = Bt_mlp2; K = 360; N = 180; KP = 384; base = e2; }
  else if (idx < e4) { src = upw;   dst = Bt_up;   K = 180; N = 48;  KP = 192; base = e3; }
  else return;
  int off = idx - base;
  int n = off / KP, k = off % KP;
  float v = (k < K && n < N) ? src[(size_t)k * N + n] : 0.f;
  dst[off] = f2bf(v);
}

// ---------------- embed (3->180) + LN1 applied, outputs window-major ----------------
__global__ __launch_bounds__(256) void k_embed(
    const float* __restrict__ x, const float* __restrict__ ew,
    const float* __restrict__ eb, const float* __restrict__ g1,
    const float* __restrict__ b1, bf16* __restrict__ tok,
    bf16* __restrict__ Aq) {
  int wrow = blockIdx.x * 4 + (threadIdx.x >> 6);
  int lane = threadIdx.x & 63;
  int token = win_to_token(wrow);
  int t = token >> 12, p = token & 4095;
  int r = p >> 6, c = p & 63;
  int gh = (t >> 2) * 64 + r, gw = (t & 3) * 64 + c;
  float x0 = x[gh * 256 + gw];
  float x1 = x[65536 + gh * 256 + gw];
  float x2 = x[131072 + gh * 256 + gw];
  float v[3];
  float s = 0.f, s2 = 0.f;
#pragma unroll
  for (int i = 0; i < 3; ++i) {
    int e = lane + i * 64;
    float vv = 0.f;
    if (e < 180) {
      vv = eb[e];
      vv = fmaf(x0, ew[e], vv);
      vv = fmaf(x1, ew[180 + e], vv);
      vv = fmaf(x2, ew[360 + e], vv);
      tok[(size_t)wrow * 180 + e] = f2bf(vv);
      s += vv; s2 = fmaf(vv, vv, s2);
    }
    v[i] = vv;
  }
#pragma unroll
  for (int off = 32; off; off >>= 1) { s += __shfl_xor(s, off); s2 += __shfl_xor(s2, off); }
  float mu = s * (1.f / 180.f);
  float rs = rsqrtf(s2 * (1.f / 180.f) - mu * mu + 1e-5f);
#pragma unroll
  for (int i = 0; i < 3; ++i) {
    int e = lane + i * 64;
    if (e < 192) {
      float a = (e < 180) ? ((v[i] - mu) * rs * g1[e] + b1[e]) : 0.f;
      Aq[(size_t)wrow * 192 + e] = f2bf(a);
    }
  }
}

// ---------------- LN2 prep ----------------
__global__ __launch_bounds__(256) void k_ln2prep(
    const bf16* __restrict__ tok, const float* __restrict__ g2,
    const float* __restrict__ b2, bf16* __restrict__ A2) {
  int wrow = blockIdx.x * 4 + (threadIdx.x >> 6);
  int lane = threadIdx.x & 63;
  float v[3];
  float s = 0.f, s2 = 0.f;
#pragma unroll
  for (int i = 0; i < 3; ++i) {
    int e = lane + i * 64;
    float vv = 0.f;
    if (e < 180) {
      vv = bf2f(tok[(size_t)wrow * 180 + e]);
      s += vv; s2 = fmaf(vv, vv, s2);
    }
    v[i] = vv;
  }
#pragma unroll
  for (int off = 32; off; off >>= 1) { s += __shfl_xor(s, off); s2 += __shfl_xor(s2, off); }
  float mu = s * (1.f / 180.f);
  float rs = rsqrtf(s2 * (1.f / 180.f) - mu * mu + 1e-5f);
#pragma unroll
  for (int i = 0; i < 3; ++i) {
    int e = lane + i * 64;
    if (e < 192) {
      float a = (e < 180) ? ((v[i] - mu) * rs * g2[e] + b2[e]) : 0.f;
      A2[(size_t)wrow * 192 + e] = f2bf(a);
    }
  }
}

// ---------------- zero head-pad cols (d=30,31) of Qp/Kp ----------------
__global__ __launch_bounds__(256) void k_padzero(bf16* __restrict__ Qp,
                                                 bf16* __restrict__ Kp) {
  int row = blockIdx.x * 256 + threadIdx.x;
#pragma unroll
  for (int hd = 0; hd < 6; ++hd) {
    *(uint32_t*)&Qp[(size_t)row * 192 + hd * 32 + 30] = 0;
    *(uint32_t*)&Kp[(size_t)row * 192 + hd * 32 + 30] = 0;
  }
}

// ---------------- MFMA GEMM (no LDS; B bf16 [n][KPAD] from L2) ----------
// EPI: 0=plain store, 1=accum into C, 2=gelu+pad store, 3=QKV split
template <int KPAD, int EPI>
__global__ __launch_bounds__(256) void k_mfma_gemm(
    const bf16* __restrict__ A, int ldA,
    const bf16* __restrict__ Bt, const float* __restrict__ bias,
    bf16* __restrict__ Cp, int ldC, int N,
    bf16* __restrict__ Qo, bf16* __restrict__ Ko, bf16* __restrict__ Vo) {
  const int tid = threadIdx.x;
  const int n0 = blockIdx.x * 64;
  const int m0 = blockIdx.y * 128;
  const int w = tid >> 6, l = tid & 63;
  const int lr = l & 15, lk = l >> 4;
  f32x4 acc[2][4];
#pragma unroll
  for (int i = 0; i < 2; ++i)
#pragma unroll
    for (int j = 0; j < 4; ++j) acc[i][j] = (f32x4){0.f, 0.f, 0.f, 0.f};
  const bf16* Arow = A + (size_t)(m0 + w * 32 + lr) * ldA + lk * 8;
  const bf16* Brow = Bt + (size_t)n0 * KPAD + lr * KPAD + lk * 8;
#pragma unroll
  for (int ks = 0; ks < KPAD / 32; ++ks) {
    short8 fa[2], fb[4];
#pragma unroll
    for (int i = 0; i < 2; ++i)
      fa[i] = *(const short8*)(Arow + (size_t)i * 16 * ldA + ks * 32);
#pragma unroll
    for (int j = 0; j < 4; ++j)
      fb[j] = *(const short8*)(Brow + (size_t)j * 16 * KPAD + ks * 32);
#pragma unroll
    for (int i = 0; i < 2; ++i)
#pragma unroll
      for (int j = 0; j < 4; ++j)
        acc[i][j] = __builtin_amdgcn_mfma_f32_16x16x32_bf16(fa[i], fb[j], acc[i][j], 0, 0, 0);
  }
#pragma unroll
  for (int i = 0; i < 2; ++i) {
    int mbase = m0 + w * 32 + i * 16 + lk * 4;
#pragma unroll
    for (int j = 0; j < 4; ++j) {
      int n = n0 + j * 16 + lr;
#pragma unroll
      for (int q = 0; q < 4; ++q) {
        int m = mbase + q;
        if (n >= N) {
          if (EPI == 2 && n < ldC) Cp[(size_t)m * ldC + n] = f2bf(0.f);
          continue;
        }
        float vv = acc[i][j][q] + bias[n];
        if (EPI == 2) {
          float u = 0.7978845608028654f * (vv + 0.044715f * vv * vv * vv);
          vv = vv / (1.f + __expf(-2.f * u));
        }
        if (EPI == 3) {
          int buf = n / 180, dp = n % 180;
          int hd = dp / 30, dd = dp % 30;
          int colp = hd * 32 + dd;
          if (buf == 0)      Qo[(size_t)m * 192 + colp] = f2bf(vv);
          else if (buf == 1) Ko[(size_t)m * 192 + colp] = f2bf(vv);
          else               Vo[(size_t)colp * 65536 + m] = f2bf(vv);
        } else {
          bf16* cp = Cp + (size_t)m * ldC + n;
          if (EPI == 1) vv += bf2f(*cp);
          *cp = f2bf(vv);
        }
      }
    }
  }
}

// ---------------- MFMA attention: block = (window, head), 4 waves ----------------
__global__ __launch_bounds__(256) void k_attn_mfma(
    const bf16* __restrict__ Qp, const bf16* __restrict__ Kp,
    const bf16* __restrict__ Vt, bf16* __restrict__ av) {
  const int blk = blockIdx.x;
  const int win = blk / 6, hd = blk % 6;
  const int tid = threadIdx.x;
  const int w = tid >> 6, l = tid & 63;
  const int lr = l & 15, lk = l >> 4;
  const float scale = 0.18257418583505536f;  // 1/sqrt(30)

  __shared__ bf16 Ks[256][40];
  __shared__ bf16 Vs[32][264];
  __shared__ bf16 Ps[4][16][264];

  {
    const bf16* src = Kp + (size_t)(win * 256 + tid) * 192 + hd * 32;
#pragma unroll
    for (int c = 0; c < 4; ++c)
      *(short8*)&Ks[tid][c * 8] = *(const short8*)(src + c * 8);
  }
  {
    int d = tid >> 3, ck = tid & 7;
    const bf16* src = Vt + (size_t)(hd * 32 + d) * 65536 + win * 256 + ck * 32;
#pragma unroll
    for (int c = 0; c < 4; ++c)
      *(short8*)&Vs[d][ck * 32 + c * 8] = *(const short8*)(src + c * 8);
  }
  __syncthreads();

  for (int qt = 0; qt < 4; ++qt) {
    const int qbase = qt * 64 + w * 16;
    short8 fq = *(const short8*)(Qp + (size_t)(win * 256 + qbase + lr) * 192 + hd * 32 + lk * 8);
    f32x4 accS[16];
#pragma unroll
    for (int kt = 0; kt < 16; ++kt) {
      short8 fk = *(const short8*)(&Ks[kt * 16 + lr][lk * 8]);
      accS[kt] = __builtin_amdgcn_mfma_f32_16x16x32_bf16(
          fk, fq, (f32x4){0.f, 0.f, 0.f, 0.f}, 0, 0, 0);
    }
    float mraw = -1e30f;
#pragma unroll
    for (int kt = 0; kt < 16; ++kt)
#pragma unroll
      for (int r = 0; r < 4; ++r) mraw = fmaxf(mraw, accS[kt][r]);
    mraw = fmaxf(mraw, __shfl_xor(mraw, 16));
    mraw = fmaxf(mraw, __shfl_xor(mraw, 32));
    const float mc = mraw * scale;
    float lsum = 0.f;
#pragma unroll
    for (int kt = 0; kt < 16; ++kt) {
      float p0 = __expf(fmaf(accS[kt][0], scale, -mc));
      float p1 = __expf(fmaf(accS[kt][1], scale, -mc));
      float p2 = __expf(fmaf(accS[kt][2], scale, -mc));
      float p3 = __expf(fmaf(accS[kt][3], scale, -mc));
      lsum += (p0 + p1) + (p2 + p3);
      uint32_t d0 = pack2(p0, p1), d1 = pack2(p2, p3);
      *(uint32_t*)&Ps[w][lr][kt * 16 + lk * 4]     = d0;
      *(uint32_t*)&Ps[w][lr][kt * 16 + lk * 4 + 2] = d1;
    }
    lsum += __shfl_xor(lsum, 16);
    lsum += __shfl_xor(lsum, 32);
    __syncthreads();
    f32x4 accO0 = (f32x4){0.f, 0.f, 0.f, 0.f};
    f32x4 accO1 = (f32x4){0.f, 0.f, 0.f, 0.f};
#pragma unroll
    for (int ks = 0; ks < 8; ++ks) {
      short8 fp = *(const short8*)(&Ps[w][lr][ks * 32 + lk * 8]);
      short8 fv0 = *(const short8*)(&Vs[lr][ks * 32 + lk * 8]);
      short8 fv1 = *(const short8*)(&Vs[16 + lr][ks * 32 + lk * 8]);
      accO0 = __builtin_amdgcn_mfma_f32_16x16x32_bf16(fp, fv0, accO0, 0, 0, 0);
      accO1 = __builtin_amdgcn_mfma_f32_16x16x32_bf16(fp, fv1, accO1, 0, 0, 0);
    }
    float invl = 1.f / lsum;
#pragma unroll
    for (int r = 0; r < 4; ++r) {
      float inv_r = __shfl(invl, lk * 4 + r);
      int row = win * 256 + qbase + lk * 4 + r;
      int d0 = lr, d1 = 16 + lr;
      if (d0 < 30) av[(size_t)row * 192 + hd * 30 + d0] = f2bf(accO0[r] * inv_r);
      if (d1 < 30) av[(size_t)row * 192 + hd * 30 + d1] = f2bf(accO1[r] * inv_r);
      if (hd == 0 && lr < 12) av[(size_t)row * 192 + 180 + lr] = f2bf(0.f);
    }
    __syncthreads();
  }
}

// ---------------- bicubic weights (jax Keys a=-0.5, half-pixel, edge renorm) ----------------
__device__ const float c_cubw[4][4] = {
    {-0.0439453125f, 0.3896484375f, 0.7275390625f, -0.0732421875f},
    {-0.0068359375f, 0.0908203125f, 0.9638671875f, -0.0478515625f},
    {-0.0478515625f, 0.9638671875f, 0.0908203125f, -0.0068359375f},
    {-0.0732421875f, 0.7275390625f, 0.3896484375f, -0.0439453125f},
};

__device__ __forceinline__ void cubw(int r, int ph, float* w, int& base) {
  base = r + ((ph < 2) ? -2 : -1);
  float sum = 0.f;
#pragma unroll
  for (int i = 0; i < 4; ++i) {
    int idx = base + i;
    float wi = (idx >= 0 && idx < 64) ? c_cubw[ph][i] : 0.f;
    w[i] = wi; sum += wi;
  }
  float inv = 1.f / sum;
#pragma unroll
  for (int i = 0; i < 4; ++i) w[i] *= inv;
}

// ---------------- blend: pixel-shuffle of up + bicubic + mask blend ----------------
__global__ __launch_bounds__(256) void k_blend(
    const bf16* __restrict__ up, const float* __restrict__ x,
    const float* __restrict__ maskp, float* __restrict__ sr) {
  int idx = blockIdx.x * 256 + threadIdx.x;
  int ch = idx >> 20;
  int rem = idx & 1048575;
  int gR = rem >> 10, gC = rem & 1023;
  int th = gR >> 8, tw = gC >> 8;
  int t = th * 4 + tw;
  int R = gR & 255, C = gC & 255;
  int r = R >> 2, a = R & 3, c = C >> 2, b = C & 3;
  float m = maskp[t];
  float outv;
  if (m > 0.5f) {
    int wi = r >> 4, u = r & 15, wj = c >> 4, v = c & 15;
    int wrow = (t * 16 + wi * 4 + wj) * 256 + u * 16 + v;
    outv = bf2f(up[(size_t)wrow * 48 + a * 12 + b * 3 + ch]);
  } else {
    float wy[4], wx[4];
    int yb, xb;
    cubw(r, a, wy, yb);
    cubw(c, b, wx, xb);
    const float* xc = x + ch * 65536;
    float neg = 0.f;
#pragma unroll
    for (int i = 0; i < 4; ++i) {
      int yi = yb + i;
      if (yi < 0 || yi > 63) continue;
      float rowsum = 0.f;
#pragma unroll
      for (int j = 0; j < 4; ++j) {
        int xj = xb + j;
        if (xj < 0 || xj > 63) continue;
        rowsum = fmaf(wx[j], xc[(th * 64 + yi) * 256 + tw * 64 + xj], rowsum);
      }
      neg = fmaf(wy[i], rowsum, neg);
    }
    outv = neg;
  }
  sr[idx] = outv;
}

// ---------------- launcher ----------------
extern "C" void kernel_launch(void* const* d_in, const int* in_sizes, int n_in,
                              void* d_out, int out_size, void* d_ws, size_t ws_size,
                              hipStream_t stream) {
  const float* x     = (const float*)d_in[0];
  const float* gu    = (const float*)d_in[1];
  const float* s1w   = (const float*)d_in[2];
  const float* s1b   = (const float*)d_in[3];
  const float* s2w   = (const float*)d_in[4];
  const float* s2b   = (const float*)d_in[5];
  const float* s3w   = (const float*)d_in[6];
  const float* s3b   = (const float*)d_in[7];
  const float* ew    = (const float*)d_in[8];
  const float* ebias = (const float*)d_in[9];
  const float* ln1g  = (const float*)d_in[10];
  const float* ln1b  = (const float*)d_in[11];
  const float* qkvw  = (const float*)d_in[12];
  const float* qkvb  = (const float*)d_in[13];
  const float* projw = (const float*)d_in[14];
  const float* projb = (const float*)d_in[15];
  const float* ln2g  = (const float*)d_in[16];
  const float* ln2b  = (const float*)d_in[17];
  const float* mlp1w = (const float*)d_in[18];
  const float* mlp1b = (const float*)d_in[19];
  const float* mlp2w = (const float*)d_in[20];
  const float* mlp2b = (const float*)d_in[21];
  const float* upw   = (const float*)d_in[22];
  const float* upb   = (const float*)d_in[23];

  float* out = (float*)d_out;
  float* sr  = out;                 // 3*1024*1024
  float* f3o = out + 3145728;       // 16*2
  float* f2o = f3o + 32;            // 16*32
  float* f1o = f2o + 512;           // 16*64

  char* ws = (char*)d_ws;
  bf16* tok  = (bf16*)(ws);                   // 65536*180 = 23,592,960 B
  bf16* ABuf = (bf16*)(ws + 23592960);        // 65536*192 = 25,165,824 B
  bf16* Qp   = (bf16*)(ws + 48758784);        // 65536*192
  bf16* Kp   = (bf16*)(ws + 73924608);        // 65536*192
  bf16* Vt   = (bf16*)(ws + 99090432);        // 192*65536
  bf16* mid  = Qp;                            // reuse Qp+Kp: 65536*384
  float* maskp   = (float*)(ws + 124256256);  // 64 B
  bf16* Bt_qkv  = (bf16*)(ws + 124256320);    // 576*192*2 = 221,184
  bf16* Bt_proj = (bf16*)(ws + 124477504);    // 192*192*2 = 73,728
  bf16* Bt_mlp1 = (bf16*)(ws + 124551232);    // 384*192*2 = 147,456
  bf16* Bt_mlp2 = (bf16*)(ws + 124698688);    // 192*384*2 = 147,456
  bf16* Bt_up   = (bf16*)(ws + 124846144);    // 64*192*2  = 24,576
  bf16* up      = (bf16*)(ws + 124870720);    // 65536*48*2 = 6,291,456 -> ends 131,162,176

  k_selector<<<16, 64, 0, stream>>>(x, gu, s1w, s1b, s2w, s2b, s3w, s3b, f1o, f2o, f3o, maskp);
  k_packB<<<1200, 256, 0, stream>>>(qkvw, projw, mlp1w, mlp2w, upw,
                                    Bt_qkv, Bt_proj, Bt_mlp1, Bt_mlp2, Bt_up);
  k_embed<<<16384, 256, 0, stream>>>(x, ew, ebias, ln1g, ln1b, tok, ABuf);
  k_padzero<<<256, 256, 0, stream>>>(Qp, Kp);
  // Q/K/V = LN1(tok) @ qkv_w + qkv_b, split + head-padded
  k_mfma_gemm<192, 3><<<dim3(9, 512), 256, 0, stream>>>(
      ABuf, 192, Bt_qkv, qkvb, nullptr, 0, 540, Qp, Kp, Vt);
  k_attn_mfma<<<1536, 256, 0, stream>>>(Qp, Kp, Vt, ABuf);
  // tok += av @ proj_w + proj_b
  k_mfma_gemm<192, 1><<<dim3(3, 512), 256, 0, stream>>>(
      ABuf, 192, Bt_proj, projb, tok, 180, 180, nullptr, nullptr, nullptr);
  k_ln2prep<<<16384, 256, 0, stream>>>(tok, ln2g, ln2b, ABuf);
  // mid = gelu(LN2(tok) @ mlp1_w + mlp1_b), zero-padded to 384 cols
  k_mfma_gemm<192, 2><<<dim3(6, 512), 256, 0, stream>>>(
      ABuf, 192, Bt_mlp1, mlp1b, mid, 384, 360, nullptr, nullptr, nullptr);
  // tok += mid @ mlp2_w + mlp2_b
  k_mfma_gemm<384, 1><<<dim3(3, 512), 256, 0, stream>>>(
      mid, 384, Bt_mlp2, mlp2b, tok, 180, 180, nullptr, nullptr, nullptr);
  // up = tok @ up_w + up_b  (K=180, garbage x zero-pad B is safe)
  k_mfma_gemm<192, 0><<<dim3(1, 512), 256, 0, stream>>>(
      tok, 180, Bt_up, upb, up, 48, 48, nullptr, nullptr, nullptr);
  k_blend<<<12288, 256, 0, stream>>>(up, x, maskp, sr);
}